// Round 4
// baseline (364.468 us; speedup 1.0000x reference)
//
#include <hip/hip_runtime.h>
#include <cstdint>

#define KDIM 4096
#define NNODE 4096
#define KSPLIT 2
#define TSTEPS 128            // K-steps of 32 over KDIM
#define THALF (TSTEPS / KSPLIT)

typedef __bf16 bf16x8 __attribute__((ext_vector_type(8)));
typedef float floatx4 __attribute__((ext_vector_type(4)));

__device__ __forceinline__ uint16_t f2b(float f) {
  union { float f; uint32_t u; } v; v.f = f;
  uint32_t u = v.u;
  return (uint16_t)((u + 0x7FFFu + ((u >> 16) & 1u)) >> 16);  // RNE
}
__device__ __forceinline__ float b2f(uint16_t h) {
  union { uint32_t u; float f; } v; v.u = ((uint32_t)h) << 16; return v.f;
}
__device__ __forceinline__ uint32_t pack2(float a, float b) {
  return (uint32_t)f2b(a) | ((uint32_t)f2b(b) << 16);
}

// Fragment layout (both GEMM operands): frag[f16][t][lane][8] where
// elem = M[f16*16 + mr][t*32 + q*8 + j], lane = q*16 + mr.
// A wave's fragment load = base + lane*16B -> one fully-coalesced 1KB dwordx4.

// ---------- supports: fp32 row-major -> bf16 fragment layout ----------
__global__ __launch_bounds__(256) void cvt_supports(
    const float* __restrict__ s0, const float* __restrict__ s1,
    uint16_t* __restrict__ d0, uint16_t* __restrict__ d1) {
  const float* src = blockIdx.z ? s1 : s0;
  uint16_t* dst = blockIdx.z ? d1 : d0;
  const int c16 = blockIdx.x, kb = blockIdx.y;      // 256 x 32
  const int col_in = threadIdx.x >> 4, k8 = threadIdx.x & 15;
  const int col = c16 * 16 + col_in;
  const int k = kb * 128 + k8 * 8;
  const float* p = src + (size_t)col * KDIM + k;
  float4 v0 = *(const float4*)p;
  float4 v1 = *(const float4*)(p + 4);
  uint4 o;
  o.x = pack2(v0.x, v0.y); o.y = pack2(v0.z, v0.w);
  o.z = pack2(v1.x, v1.y); o.w = pack2(v1.z, v1.w);
  size_t off = ((size_t)(c16 * 128 + kb * 4 + (k8 >> 2))) * 512 +
               (size_t)((k8 & 3) * 16 + col_in) * 8;
  *(uint4*)(dst + off) = o;
}

// ---------- X1 (gemm1 A): rows (b,[feats(2);prev(16)]) -> fragment layout ----------
__global__ __launch_bounds__(256) void pack_x1(
    const float* __restrict__ inp, const float* __restrict__ st,
    uint16_t* __restrict__ X1) {
  const int r16 = blockIdx.x, kb = blockIdx.y;      // 72 x 32
  const int row_in = threadIdx.x >> 4, k8 = threadIdx.x & 15;
  const int row = r16 * 16 + row_in;
  const int k = kb * 128 + k8 * 8;
  int b = row / 18, c = row - b * 18;
  const float* p = (c < 2) ? (inp + (size_t)b * 8192 + (size_t)c * 4096 + k)
                           : (st + (size_t)b * 65536 + (size_t)(c - 2) * 4096 + k);
  float4 v0 = *(const float4*)p;
  float4 v1 = *(const float4*)(p + 4);
  uint4 o;
  o.x = pack2(v0.x, v0.y); o.y = pack2(v0.z, v0.w);
  o.z = pack2(v1.x, v1.y); o.w = pack2(v1.z, v1.w);
  size_t off = ((size_t)(r16 * 128 + kb * 4 + (k8 >> 2))) * 512 +
               (size_t)((k8 & 3) * 16 + row_in) * 8;
  *(uint4*)(X1 + off) = o;
}

// direct global->LDS, 16B per lane; LDS dest is wave-uniform base + lane*16
__device__ __forceinline__ void gl_lds16(const uint16_t* g, uint16_t* l) {
  __builtin_amdgcn_global_load_lds(
      (const __attribute__((address_space(1))) uint32_t*)g,
      (__attribute__((address_space(3))) uint32_t*)l, 16, 0, 0);
}

// ---------- 128x256-tile LDS-shared fragment GEMM (R4) ----------
// C = A * S^T, operands pre-packed in fragment layout. R3 post-mortem: the
// 128x128 structure is LDS-BW-bound (48KB traffic / 310cy MFMA per chunk =
// 155 B/cy needed > ~100 effective). R4 doubles arithmetic intensity:
// block tile 128x256, 4 waves (2x2), WAVE tile 64x128 (4x8 frags), 16x16x32
// MFMA, split-K=2. Per chunk (K=32): stage 24 frags (8A+16B = 24KB), do
// 128 MFMA = 620cy -> 72KB/620cy = 116 B/cy <= LDS peak: ~MFMA-bound.
// THREE LDS buffers (72KB -> 2 blocks/CU), depth-2 staging with counted
// vmcnt(6); register double-buffer with counted lgkmcnt(12) (reads issued a
// full iter ahead). Buffer index rotates mod 3 at runtime (address math
// only; register sets statically named - rule #20). Grids: gemm1 576
// blocks, gemm2 512 = exactly one 2-block/CU residency round.
template <int MODE>
__global__ __launch_bounds__(256, 2) void gemm_frag(
    const uint16_t* __restrict__ Af, const uint16_t* __restrict__ S0f,
    const uint16_t* __restrict__ S1f, uint16_t* __restrict__ D) {
  constexpr int CPB = (MODE == 1) ? 18 : 16;
  constexpr int OUTC = (MODE == 1) ? 36 : 32;
  constexpr size_t PSTRIDE = (size_t)64 * OUTC * NNODE;
  constexpr int NCH = THALF;       // 64 chunks of K=32 (one t-frag each)

  __shared__ uint16_t sAB[3][24][512];  // 72 KiB: [buf][frag slot][elems]

  const int lane = threadIdx.x & 63, wave = threadIdx.x >> 6;
  const int wr = wave >> 1, wc = wave & 1;
  const int s = blockIdx.z & 1, ks = blockIdx.z >> 1;
  const uint16_t* __restrict__ Bf = s ? S1f : S0f;
  const int yF = blockIdx.y * 8;    // A frag-row base (8 frags = 128 rows)
  const int xF = blockIdx.x * 16;   // B frag-col base (16 frags = 256 cols)
  const int tBeg = ks * THALF;

  // staging: 24 frags/chunk, each wave stages 6: fid = wave*6 + i.
  // fid 0-7 -> A frag-rows yF+fid (slots 0-7); fid 8-23 -> B frag-cols
  // xF+fid-8 (slots 8-23). slot == fid.
  const uint16_t* Gp[6];
#pragma unroll
  for (int i = 0; i < 6; ++i) {
    int fid = wave * 6 + i;
    bool isA = fid < 8;
    int fr = isA ? (yF + fid) : (xF + fid - 8);
    const uint16_t* base = isA ? Af : Bf;
    Gp[i] = base + ((size_t)fr * 128 + tBeg) * 512 + (size_t)lane * 8;
  }

  floatx4 acc[4][8];
#pragma unroll
  for (int i = 0; i < 4; ++i)
#pragma unroll
    for (int j = 0; j < 8; ++j) acc[i][j] = (floatx4){0.f, 0.f, 0.f, 0.f};

  auto STAGE = [&](int bi, int c) {
    uint16_t* l = &sAB[bi][wave * 6][0];
    const size_t off = (size_t)c * 512;
#pragma unroll
    for (int i = 0; i < 6; ++i)
      gl_lds16(Gp[i] + off, l + (size_t)i * 512);
  };

  auto LDREG = [&](int bi, bf16x8* a, bf16x8* b) {
    const uint16_t* base = &sAB[bi][0][lane * 8];
#pragma unroll
    for (int rt = 0; rt < 4; ++rt)
      a[rt] = *(const bf16x8*)(base + (size_t)(wr * 4 + rt) * 512);
#pragma unroll
    for (int ct = 0; ct < 8; ++ct)
      b[ct] = *(const bf16x8*)(base + (size_t)(8 + wc * 8 + ct) * 512);
  };

  auto MFMA32 = [&](bf16x8* a, bf16x8* b) {
    __builtin_amdgcn_s_setprio(1);
#pragma unroll
    for (int rt = 0; rt < 4; ++rt)
#pragma unroll
      for (int ct = 0; ct < 8; ++ct)
        acc[rt][ct] = __builtin_amdgcn_mfma_f32_16x16x32_bf16(
            a[rt], b[ct], acc[rt][ct], 0, 0, 0);
    __builtin_amdgcn_s_setprio(0);
  };

  // prologue: chunks 0,1 staged; chunk 0 -> regset A
  STAGE(0, 0);
  STAGE(1, 1);
  asm volatile("s_waitcnt vmcnt(6)" ::: "memory");   // chunk 0 landed
  __builtin_amdgcn_sched_barrier(0);
  __builtin_amdgcn_s_barrier();
  __builtin_amdgcn_sched_barrier(0);
  bf16x8 aA[4], bA[8], aB[4], bB[8];
  LDREG(0, aA, bA);

  int bN = 1, bS = 2;  // buffer of chunk c+1 (read-next), chunk c+2 (stage)
#define GEMM_ITER(CC, CURA, CURB, NXTA, NXTB)                               \
  {                                                                         \
    int cl = (CC) + 2;                                                      \
    if (cl > NCH - 1) cl = NCH - 1; /* clamped redundant tail stage */      \
    STAGE(bS, cl);                                                          \
    asm volatile("s_waitcnt vmcnt(6)" ::: "memory");                        \
    __builtin_amdgcn_sched_barrier(0);                                      \
    __builtin_amdgcn_s_barrier();                                           \
    __builtin_amdgcn_sched_barrier(0);                                      \
    LDREG(bN, NXTA, NXTB);                                                  \
    asm volatile("s_waitcnt lgkmcnt(12)" ::: "memory");                     \
    __builtin_amdgcn_sched_barrier(0);                                      \
    MFMA32(CURA, CURB);                                                     \
    __builtin_amdgcn_sched_barrier(0);                                      \
    bN = (bN == 2) ? 0 : bN + 1;                                            \
    bS = (bS == 2) ? 0 : bS + 1;                                            \
  }

  for (int c = 0; c < NCH; c += 2) {
    GEMM_ITER(c,     aA, bA, aB, bB)   // MFMA chunk c   (set A), load c+1 -> B
    GEMM_ITER(c + 1, aB, bB, aA, bA)   // MFMA chunk c+1 (set B), load c+2 -> A
  }
#undef GEMM_ITER

  uint16_t* Dp = D + (size_t)ks * PSTRIDE;
  // epilogue: C/D layout col=lane&15, row=(lane>>4)*4+reg; D row-major bf16
#pragma unroll
  for (int rt = 0; rt < 4; ++rt) {
#pragma unroll
    for (int r = 0; r < 4; ++r) {
      int rowg = yF * 16 + wr * 64 + rt * 16 + (lane >> 4) * 4 + r;
      int b = rowg / CPB, c = rowg - b * CPB;
      int jj;
      if (MODE == 1) jj = (c < 2) ? (2 * s + c) : (4 + 16 * s + (c - 2));
      else jj = 16 * s + c;
      uint16_t* drow = Dp + (size_t)(b * OUTC + jj) * NNODE;
#pragma unroll
      for (int ct = 0; ct < 8; ++ct) {
        int colg = xF * 16 + wc * 128 + ct * 16 + (lane & 15);
        drow[colg] = f2b(acc[rt][ct][r]);
      }
    }
  }
}

// ---------- stage2: r,u gates; X2 = r*prev -> fragment layout via LDS transpose ----------
__global__ __launch_bounds__(256) void stage2(
    const uint16_t* __restrict__ P1, const float* __restrict__ state,
    const float* __restrict__ rk, const float* __restrict__ uk,
    uint16_t* __restrict__ X2f, float* __restrict__ U) {
  constexpr size_t PS = (size_t)64 * 36 * NNODE;
  __shared__ float s_rk[576], s_uk[576];
  __shared__ uint16_t s_x2[16 * 264];  // [k][i], padded stride (264) vs 256
  for (int i = threadIdx.x; i < 576; i += 256) { s_rk[i] = rk[i]; s_uk[i] = uk[i]; }
  __syncthreads();
  const int b = blockIdx.x >> 4, nb = blockIdx.x & 15;
  const int i = threadIdx.x;
  const int n = nb * 256 + i;
  float hs[36];
  const uint16_t* p = P1 + (size_t)b * 36 * NNODE + n;
#pragma unroll
  for (int j = 0; j < 36; ++j)
    hs[j] = b2f(p[(size_t)j * NNODE]) + b2f(p[PS + (size_t)j * NNODE]);
  float ar[16], au[16];
#pragma unroll
  for (int k = 0; k < 16; ++k) { ar[k] = 0.f; au[k] = 0.f; }
#pragma unroll
  for (int j = 0; j < 36; ++j) {
    float h = hs[j];
#pragma unroll
    for (int k = 0; k < 16; ++k) {
      ar[k] += h * s_rk[j * 16 + k];
      au[k] += h * s_uk[j * 16 + k];
    }
  }
  const float* sp = state + (size_t)b * 65536 + n;
#pragma unroll
  for (int k = 0; k < 16; ++k) {
    float r = 1.f / (1.f + __expf(-ar[k]));
    float uu = 1.f / (1.f + __expf(-au[k]));
    float prev = sp[(size_t)k * NNODE];
    s_x2[k * 264 + i] = f2b(r * prev);
    U[(size_t)(b * 16 + k) * NNODE + n] = uu;
  }
  __syncthreads();
  // flush 4096 bf16 (16 k x 256 n) to fragment layout: contiguous 8KB region.
  // global o = tl*512 + (qq*16+kk)*8 + jj ; element = (row b*16+kk, n nb*256 + tl*32+qq*8+jj)
  uint16_t* region = X2f + ((size_t)b * 128 + nb * 8) * 512;
#pragma unroll
  for (int rr = 0; rr < 2; ++rr) {
    int fid = rr * 256 + i;
    int kk = fid & 15, qq = (fid >> 4) & 3, tl = fid >> 6;
    uint4 v = *(const uint4*)&s_x2[kk * 264 + tl * 32 + qq * 8];
    *(uint4*)(region + (size_t)fid * 8) = v;
  }
}

// ---------- stage4: c = tanh([h;D3]*ck); z = u*prev + (1-u)*c ----------
// OUTPUT LAYOUT: z is (B, N, U) reshaped -> out[b*65536 + n*16 + k]
__global__ __launch_bounds__(256) void stage4(
    const uint16_t* __restrict__ P1, const uint16_t* __restrict__ P3,
    const float* __restrict__ U, const float* __restrict__ state,
    const float* __restrict__ ck, float* __restrict__ out) {
  constexpr size_t PS1 = (size_t)64 * 36 * NNODE;
  constexpr size_t PS3 = (size_t)64 * 32 * NNODE;
  __shared__ float s_ck[576];
  for (int i = threadIdx.x; i < 576; i += 256) s_ck[i] = ck[i];
  __syncthreads();
  int idx = blockIdx.x * 256 + threadIdx.x;
  int b = idx >> 12, n = idx & 4095;
  float hv[36];
  const uint16_t* p1 = P1 + (size_t)b * 36 * NNODE + n;
#pragma unroll
  for (int j = 0; j < 4; ++j)
    hv[j] = b2f(p1[(size_t)j * NNODE]) + b2f(p1[PS1 + (size_t)j * NNODE]);
  const uint16_t* p3 = P3 + (size_t)b * 32 * NNODE + n;
#pragma unroll
  for (int j = 0; j < 32; ++j)
    hv[4 + j] = b2f(p3[(size_t)j * NNODE]) + b2f(p3[PS3 + (size_t)j * NNODE]);
  float ac[16];
#pragma unroll
  for (int k = 0; k < 16; ++k) ac[k] = 0.f;
#pragma unroll
  for (int j = 0; j < 36; ++j) {
    float h = hv[j];
#pragma unroll
    for (int k = 0; k < 16; ++k) ac[k] += h * s_ck[j * 16 + k];
  }
  const float* sp = state + (size_t)b * 65536 + n;
  const float* up = U + (size_t)b * 16 * NNODE + n;
  float z[16];
#pragma unroll
  for (int k = 0; k < 16; ++k) {
    float e = __expf(2.f * ac[k]);
    float c = 1.f - 2.f / (e + 1.f);  // tanh, saturates at +/-inf
    float uu = up[(size_t)k * NNODE];
    float prev = sp[(size_t)k * NNODE];
    z[k] = uu * prev + (1.f - uu) * c;
  }
  float4* po = (float4*)(out + (size_t)b * 65536 + (size_t)n * 16);
#pragma unroll
  for (int k4 = 0; k4 < 4; ++k4)
    po[k4] = make_float4(z[k4 * 4], z[k4 * 4 + 1], z[k4 * 4 + 2], z[k4 * 4 + 3]);
}

extern "C" void kernel_launch(void* const* d_in, const int* in_sizes, int n_in,
                              void* d_out, int out_size, void* d_ws, size_t ws_size,
                              hipStream_t stream) {
  const float* inputs = (const float*)d_in[0];
  const float* state = (const float*)d_in[1];
  const float* s0 = (const float*)d_in[2];
  const float* s1 = (const float*)d_in[3];
  const float* rk = (const float*)d_in[4];
  const float* uk = (const float*)d_in[5];
  const float* ck = (const float*)d_in[6];
  float* out = (float*)d_out;
  char* ws = (char*)d_ws;

  // workspace layout (bytes); X2f aliases X1f (dead after gemm1)
  uint16_t* S0f = (uint16_t*)(ws);                  // 33,554,432
  uint16_t* S1f = (uint16_t*)(ws + 33554432);       // 33,554,432
  uint16_t* X1f = (uint16_t*)(ws + 67108864);       // 9,437,184   (1152 x 4096 bf16, frag)
  uint16_t* X2f = (uint16_t*)(ws + 67108864);       // 8,388,608   (aliases X1f, frag)
  uint16_t* P1 = (uint16_t*)(ws + 76546048);        // 2 x 18,874,368 (split-K partials)
  float* U = (float*)(ws + 114294784);              // 16,777,216
  uint16_t* P3 = (uint16_t*)(ws + 131072000);       // 2 x 16,777,216 (split-K partials)
  // total 164,626,432 bytes

  cvt_supports<<<dim3(256, 32, 2), 256, 0, stream>>>(s0, s1, S0f, S1f);
  pack_x1<<<dim3(72, 32), 256, 0, stream>>>(inputs, state, X1f);
  gemm_frag<1><<<dim3(16, 9, 2 * KSPLIT), 256, 0, stream>>>(X1f, S0f, S1f, P1);
  stage2<<<1024, 256, 0, stream>>>(P1, state, rk, uk, X2f, U);
  gemm_frag<3><<<dim3(16, 8, 2 * KSPLIT), 256, 0, stream>>>(X2f, S0f, S1f, P3);
  stage4<<<1024, 256, 0, stream>>>(P1, P3, U, state, ck, out);
}

// Round 5
// 345.640 us; speedup vs baseline: 1.0545x; 1.0545x over previous
//
#include <hip/hip_runtime.h>
#include <cstdint>

#define KDIM 4096
#define NNODE 4096
#define TSTEPS 128            // K-steps of 32 over KDIM

typedef __bf16 bf16x8 __attribute__((ext_vector_type(8)));
typedef float floatx4 __attribute__((ext_vector_type(4)));

__device__ __forceinline__ uint16_t f2b(float f) {
  union { float f; uint32_t u; } v; v.f = f;
  uint32_t u = v.u;
  return (uint16_t)((u + 0x7FFFu + ((u >> 16) & 1u)) >> 16);  // RNE
}
__device__ __forceinline__ float b2f(uint16_t h) {
  union { uint32_t u; float f; } v; v.u = ((uint32_t)h) << 16; return v.f;
}
__device__ __forceinline__ uint32_t pack2(float a, float b) {
  return (uint32_t)f2b(a) | ((uint32_t)f2b(b) << 16);
}

// Fragment layout (both GEMM operands): frag[f16][t][lane][8] where
// elem = M[f16*16 + mr][t*32 + q*8 + j], lane = q*16 + mr.
// A wave's fragment load = base + lane*16B -> one fully-coalesced 1KB dwordx4.

// ---------- supports: fp32 row-major -> bf16 fragment layout ----------
__global__ __launch_bounds__(256) void cvt_supports(
    const float* __restrict__ s0, const float* __restrict__ s1,
    uint16_t* __restrict__ d0, uint16_t* __restrict__ d1) {
  const float* src = blockIdx.z ? s1 : s0;
  uint16_t* dst = blockIdx.z ? d1 : d0;
  const int c16 = blockIdx.x, kb = blockIdx.y;      // 256 x 32
  const int col_in = threadIdx.x >> 4, k8 = threadIdx.x & 15;
  const int col = c16 * 16 + col_in;
  const int k = kb * 128 + k8 * 8;
  const float* p = src + (size_t)col * KDIM + k;
  float4 v0 = *(const float4*)p;
  float4 v1 = *(const float4*)(p + 4);
  uint4 o;
  o.x = pack2(v0.x, v0.y); o.y = pack2(v0.z, v0.w);
  o.z = pack2(v1.x, v1.y); o.w = pack2(v1.z, v1.w);
  size_t off = ((size_t)(c16 * 128 + kb * 4 + (k8 >> 2))) * 512 +
               (size_t)((k8 & 3) * 16 + col_in) * 8;
  *(uint4*)(dst + off) = o;
}

// ---------- X1 (gemm1 A): rows (b,[feats(2);prev(16)]) -> fragment layout ----------
__global__ __launch_bounds__(256) void pack_x1(
    const float* __restrict__ inp, const float* __restrict__ st,
    uint16_t* __restrict__ X1) {
  const int r16 = blockIdx.x, kb = blockIdx.y;      // 72 x 32
  const int row_in = threadIdx.x >> 4, k8 = threadIdx.x & 15;
  const int row = r16 * 16 + row_in;
  const int k = kb * 128 + k8 * 8;
  int b = row / 18, c = row - b * 18;
  const float* p = (c < 2) ? (inp + (size_t)b * 8192 + (size_t)c * 4096 + k)
                           : (st + (size_t)b * 65536 + (size_t)(c - 2) * 4096 + k);
  float4 v0 = *(const float4*)p;
  float4 v1 = *(const float4*)(p + 4);
  uint4 o;
  o.x = pack2(v0.x, v0.y); o.y = pack2(v0.z, v0.w);
  o.z = pack2(v1.x, v1.y); o.w = pack2(v1.z, v1.w);
  size_t off = ((size_t)(r16 * 128 + kb * 4 + (k8 >> 2))) * 512 +
               (size_t)((k8 & 3) * 16 + row_in) * 8;
  *(uint4*)(X1 + off) = o;
}

// direct global->LDS, 16B per lane; LDS dest is wave-uniform base + lane*16
__device__ __forceinline__ void gl_lds16(const uint16_t* g, uint16_t* l) {
  __builtin_amdgcn_global_load_lds(
      (const __attribute__((address_space(1))) uint32_t*)g,
      (__attribute__((address_space(3))) uint32_t*)l, 16, 0, 0);
}

// ---------- 1-block-per-CU full-K fragment GEMM (R5) ----------
// R4 post-mortem: per-CU LDS BW (~128 B/cy, ds_read_b128 ~12cy) is SHARED by
// co-resident blocks -> 2 blocks/CU doubled demand (cap 45%); plus grid
// quantization (576/512). R5: ONE 512-thread block per CU, grids exactly 256,
// full K=4096 (no split-K, no partials):
//   MODE1: tile 144x256 (1152=8x144), waves 1x8, wave tile 144x32.
//          LDS demand 120KB / 698 MFMA cy = 172 B/cy -> cap ~74%.
//   MODE3: tile 128x256, waves 2x4, wave tile 64x64. 88KB/621cy -> cap ~90%.
// Staging: 4 LDS buffers, depth-3 counted vmcnt (stage chunk c+3; wait
// vmcnt(2*LPW) so chunk c+1 landed, c+2/c+3 in flight). Per-wave loads/chunk
// uniform (MODE1: 25 real frags + 7 idempotent pad loads = 4/wave; MODE3:
// 24 = 3/wave) so vmcnt literals are constant. Register double-buffer:
// LDREG chunk c+1 after barrier, counted lgkmcnt waits only on the PREVIOUS
// chunk's reads -> MFMA never waits on same-iter ds_reads. Buffer safety:
// staged buf's old chunk was read at iter c-2; barrier at c-1 intervenes.
template <int MODE>
__global__ __launch_bounds__(512, 2) void gemm_frag(
    const uint16_t* __restrict__ Af, const uint16_t* __restrict__ S0f,
    const uint16_t* __restrict__ S1f, uint16_t* __restrict__ D) {
  constexpr int CPB   = (MODE == 1) ? 18 : 16;
  constexpr int OUTC  = (MODE == 1) ? 36 : 32;
  constexpr int MFR   = (MODE == 1) ? 9 : 8;   // A frag-rows per tile
  constexpr int WM    = (MODE == 1) ? 1 : 2;   // wave grid M
  constexpr int WN    = 8 / WM;                // wave grid N
  constexpr int AR    = MFR / WM;              // a-frags per wave (9 / 4)
  constexpr int BR    = 16 / WN;               // b-frags per wave (2 / 4)
  constexpr int NREAL = MFR + 16;              // 25 / 24
  constexpr int SLOTS = (NREAL + 7) & ~7;      // 32 / 24
  constexpr int LPW   = SLOTS / 8;             // loads per wave (4 / 3)
  constexpr int NCH   = TSTEPS;                // 128 chunks of K=32 (full K)

  __shared__ uint16_t sAB[4][SLOTS][512];      // 128 KiB / 96 KiB

  const int lane = threadIdx.x & 63, wave = threadIdx.x >> 6;
  const int wr = wave / WN, wc = wave % WN;
  const int s = blockIdx.z;
  const uint16_t* __restrict__ Bf = s ? S1f : S0f;
  const int yF = blockIdx.y * MFR;   // A frag-row base
  const int xF = blockIdx.x * 16;    // B frag-col base (256 cols)

  // staging: wave stages slots [wave*LPW, wave*LPW+LPW).
  // slot < MFR: A frag yF+slot; slot < NREAL: B frag xF+slot-MFR;
  // else pad -> duplicate A frag yF (idempotent, L1-hot).
  const uint16_t* Gp[LPW];
#pragma unroll
  for (int i = 0; i < LPW; ++i) {
    int sid = wave * LPW + i;
    const uint16_t* base;
    int fr;
    if (sid < MFR)        { base = Af; fr = yF + sid; }
    else if (sid < NREAL) { base = Bf; fr = xF + sid - MFR; }
    else                  { base = Af; fr = yF; }
    Gp[i] = base + (size_t)fr * (TSTEPS * 512) + (size_t)lane * 8;
  }

  floatx4 acc[AR][BR];
#pragma unroll
  for (int i = 0; i < AR; ++i)
#pragma unroll
    for (int j = 0; j < BR; ++j) acc[i][j] = (floatx4){0.f, 0.f, 0.f, 0.f};

  auto STAGE = [&](int bi, int c) {
    uint16_t* l = &sAB[bi][wave * LPW][0];
    const size_t off = (size_t)c * 512;
#pragma unroll
    for (int i = 0; i < LPW; ++i)
      gl_lds16(Gp[i] + off, l + (size_t)i * 512);
  };

  auto LDREG = [&](int bi, bf16x8* a, bf16x8* b) {
    const uint16_t* base = &sAB[bi][0][lane * 8];
#pragma unroll
    for (int rt = 0; rt < AR; ++rt)
      a[rt] = *(const bf16x8*)(base + (size_t)(wr * AR + rt) * 512);
#pragma unroll
    for (int ct = 0; ct < BR; ++ct)
      b[ct] = *(const bf16x8*)(base + (size_t)(MFR + wc * BR + ct) * 512);
  };

  auto MFMAALL = [&](bf16x8* a, bf16x8* b) {
    __builtin_amdgcn_s_setprio(1);
#pragma unroll
    for (int rt = 0; rt < AR; ++rt)
#pragma unroll
      for (int ct = 0; ct < BR; ++ct)
        acc[rt][ct] = __builtin_amdgcn_mfma_f32_16x16x32_bf16(
            a[rt], b[ct], acc[rt][ct], 0, 0, 0);
    __builtin_amdgcn_s_setprio(0);
  };

  auto waitVM = [&] {  // chunk c+1 landed; 2 chunks (2*LPW loads) in flight
    if constexpr (MODE == 1) asm volatile("s_waitcnt vmcnt(8)" ::: "memory");
    else                     asm volatile("s_waitcnt vmcnt(6)" ::: "memory");
  };
  auto waitLG = [&] {  // previous chunk's ds_reads done; current LGK in flight
    if constexpr (MODE == 1) asm volatile("s_waitcnt lgkmcnt(11)" ::: "memory");
    else                     asm volatile("s_waitcnt lgkmcnt(8)" ::: "memory");
  };

  // prologue: chunks 0,1,2 staged; chunk 0 -> regset A
  STAGE(0, 0);
  STAGE(1, 1);
  STAGE(2, 2);
  waitVM();
  __builtin_amdgcn_sched_barrier(0);
  __builtin_amdgcn_s_barrier();
  __builtin_amdgcn_sched_barrier(0);
  bf16x8 aA[AR], bA[BR], aB[AR], bB[BR];
  LDREG(0, aA, bA);

#define GITER(J, SB, RB, CA, CB, NA, NB)                                    \
  {                                                                         \
    int cl = c0 + 3 + (J);                                                  \
    if (cl > NCH - 1) cl = NCH - 1; /* clamped redundant tail stage */      \
    STAGE((SB), cl);                                                        \
    waitVM();                                                               \
    __builtin_amdgcn_sched_barrier(0);                                      \
    __builtin_amdgcn_s_barrier();                                           \
    __builtin_amdgcn_sched_barrier(0);                                      \
    LDREG((RB), NA, NB);                                                    \
    waitLG();                                                               \
    __builtin_amdgcn_sched_barrier(0);                                      \
    MFMAALL(CA, CB);                                                        \
    __builtin_amdgcn_sched_barrier(0);                                      \
  }

  for (int m = 0; m < NCH / 4; ++m) {
    const int c0 = m * 4;
    GITER(0, 3, 1, aA, bA, aB, bB)   // MFMA chunk c0   (A), load c0+1 -> B
    GITER(1, 0, 2, aB, bB, aA, bA)   // MFMA chunk c0+1 (B), load c0+2 -> A
    GITER(2, 1, 3, aA, bA, aB, bB)
    GITER(3, 2, 0, aB, bB, aA, bA)
  }
#undef GITER

  // epilogue: C/D layout col=lane&15, row=(lane>>4)*4+reg; D row-major bf16
#pragma unroll
  for (int rt = 0; rt < AR; ++rt) {
#pragma unroll
    for (int r = 0; r < 4; ++r) {
      int rowg = (yF + wr * AR + rt) * 16 + (lane >> 4) * 4 + r;
      int b = rowg / CPB, c = rowg - b * CPB;
      int jj;
      if (MODE == 1) jj = (c < 2) ? (2 * s + c) : (4 + 16 * s + (c - 2));
      else jj = 16 * s + c;
      uint16_t* drow = D + (size_t)(b * OUTC + jj) * NNODE;
#pragma unroll
      for (int ct = 0; ct < BR; ++ct) {
        int colg = xF * 16 + (wc * BR + ct) * 16 + (lane & 15);
        drow[colg] = f2b(acc[rt][ct][r]);
      }
    }
  }
}

// ---------- stage2: r,u gates; X2 = r*prev -> fragment layout via LDS transpose ----------
__global__ __launch_bounds__(256) void stage2(
    const uint16_t* __restrict__ P1, const float* __restrict__ state,
    const float* __restrict__ rk, const float* __restrict__ uk,
    uint16_t* __restrict__ X2f, float* __restrict__ U) {
  __shared__ float s_rk[576], s_uk[576];
  __shared__ uint16_t s_x2[16 * 264];  // [k][i], padded stride (264) vs 256
  for (int i = threadIdx.x; i < 576; i += 256) { s_rk[i] = rk[i]; s_uk[i] = uk[i]; }
  __syncthreads();
  const int b = blockIdx.x >> 4, nb = blockIdx.x & 15;
  const int i = threadIdx.x;
  const int n = nb * 256 + i;
  float hs[36];
  const uint16_t* p = P1 + (size_t)b * 36 * NNODE + n;
#pragma unroll
  for (int j = 0; j < 36; ++j)
    hs[j] = b2f(p[(size_t)j * NNODE]);   // full sums now (no split-K partials)
  float ar[16], au[16];
#pragma unroll
  for (int k = 0; k < 16; ++k) { ar[k] = 0.f; au[k] = 0.f; }
#pragma unroll
  for (int j = 0; j < 36; ++j) {
    float h = hs[j];
#pragma unroll
    for (int k = 0; k < 16; ++k) {
      ar[k] += h * s_rk[j * 16 + k];
      au[k] += h * s_uk[j * 16 + k];
    }
  }
  const float* sp = state + (size_t)b * 65536 + n;
#pragma unroll
  for (int k = 0; k < 16; ++k) {
    float r = 1.f / (1.f + __expf(-ar[k]));
    float uu = 1.f / (1.f + __expf(-au[k]));
    float prev = sp[(size_t)k * NNODE];
    s_x2[k * 264 + i] = f2b(r * prev);
    U[(size_t)(b * 16 + k) * NNODE + n] = uu;
  }
  __syncthreads();
  // flush 4096 bf16 (16 k x 256 n) to fragment layout: contiguous 8KB region.
  uint16_t* region = X2f + ((size_t)b * 128 + nb * 8) * 512;
#pragma unroll
  for (int rr = 0; rr < 2; ++rr) {
    int fid = rr * 256 + i;
    int kk = fid & 15, qq = (fid >> 4) & 3, tl = fid >> 6;
    uint4 v = *(const uint4*)&s_x2[kk * 264 + tl * 32 + qq * 8];
    *(uint4*)(region + (size_t)fid * 8) = v;
  }
}

// ---------- stage4: c = tanh([h;D3]*ck); z = u*prev + (1-u)*c ----------
// OUTPUT LAYOUT: z is (B, N, U) reshaped -> out[b*65536 + n*16 + k]
__global__ __launch_bounds__(256) void stage4(
    const uint16_t* __restrict__ P1, const uint16_t* __restrict__ P3,
    const float* __restrict__ U, const float* __restrict__ state,
    const float* __restrict__ ck, float* __restrict__ out) {
  __shared__ float s_ck[576];
  for (int i = threadIdx.x; i < 576; i += 256) s_ck[i] = ck[i];
  __syncthreads();
  int idx = blockIdx.x * 256 + threadIdx.x;
  int b = idx >> 12, n = idx & 4095;
  float hv[36];
  const uint16_t* p1 = P1 + (size_t)b * 36 * NNODE + n;
#pragma unroll
  for (int j = 0; j < 4; ++j)
    hv[j] = b2f(p1[(size_t)j * NNODE]);
  const uint16_t* p3 = P3 + (size_t)b * 32 * NNODE + n;
#pragma unroll
  for (int j = 0; j < 32; ++j)
    hv[4 + j] = b2f(p3[(size_t)j * NNODE]);
  float ac[16];
#pragma unroll
  for (int k = 0; k < 16; ++k) ac[k] = 0.f;
#pragma unroll
  for (int j = 0; j < 36; ++j) {
    float h = hv[j];
#pragma unroll
    for (int k = 0; k < 16; ++k) ac[k] += h * s_ck[j * 16 + k];
  }
  const float* sp = state + (size_t)b * 65536 + n;
  const float* up = U + (size_t)b * 16 * NNODE + n;
  float z[16];
#pragma unroll
  for (int k = 0; k < 16; ++k) {
    float e = __expf(2.f * ac[k]);
    float c = 1.f - 2.f / (e + 1.f);  // tanh, saturates at +/-inf
    float uu = up[(size_t)k * NNODE];
    float prev = sp[(size_t)k * NNODE];
    z[k] = uu * prev + (1.f - uu) * c;
  }
  float4* po = (float4*)(out + (size_t)b * 65536 + (size_t)n * 16);
#pragma unroll
  for (int k4 = 0; k4 < 4; ++k4)
    po[k4] = make_float4(z[k4 * 4], z[k4 * 4 + 1], z[k4 * 4 + 2], z[k4 * 4 + 3]);
}

extern "C" void kernel_launch(void* const* d_in, const int* in_sizes, int n_in,
                              void* d_out, int out_size, void* d_ws, size_t ws_size,
                              hipStream_t stream) {
  const float* inputs = (const float*)d_in[0];
  const float* state = (const float*)d_in[1];
  const float* s0 = (const float*)d_in[2];
  const float* s1 = (const float*)d_in[3];
  const float* rk = (const float*)d_in[4];
  const float* uk = (const float*)d_in[5];
  const float* ck = (const float*)d_in[6];
  float* out = (float*)d_out;
  char* ws = (char*)d_ws;

  // workspace layout (bytes); X2f aliases X1f (dead after gemm1)
  uint16_t* S0f = (uint16_t*)(ws);                  // 33,554,432
  uint16_t* S1f = (uint16_t*)(ws + 33554432);       // 33,554,432
  uint16_t* X1f = (uint16_t*)(ws + 67108864);       // 9,437,184   (1152 x 4096 bf16, frag)
  uint16_t* X2f = (uint16_t*)(ws + 67108864);       // 8,388,608   (aliases X1f, frag)
  uint16_t* P1 = (uint16_t*)(ws + 76546048);        // 18,874,368  (full sums, no split-K)
  float* U = (float*)(ws + 114294784);              // 16,777,216
  uint16_t* P3 = (uint16_t*)(ws + 131072000);       // 16,777,216  (full sums)
  // total within 164,626,432 bytes

  cvt_supports<<<dim3(256, 32, 2), 256, 0, stream>>>(s0, s1, S0f, S1f);
  pack_x1<<<dim3(72, 32), 256, 0, stream>>>(inputs, state, X1f);
  gemm_frag<1><<<dim3(16, 8, 2), 512, 0, stream>>>(X1f, S0f, S1f, P1);
  stage2<<<1024, 256, 0, stream>>>(P1, state, rk, uk, X2f, U);
  gemm_frag<3><<<dim3(16, 8, 2), 512, 0, stream>>>(X2f, S0f, S1f, P3);
  stage4<<<1024, 256, 0, stream>>>(P1, P3, U, state, ck, out);
}